// Round 3
// baseline (787.450 us; speedup 1.0000x reference)
//
#include <hip/hip_runtime.h>

// Problem constants (reference: N=100000, E=1600000, IN=128, OUT=256)
#define NODES 100000
#define EDGES 1600000
#define FIN   128
#define FOUT  256

typedef __bf16 bf16;
typedef __bf16 bf16x8 __attribute__((ext_vector_type(8)));
typedef __bf16 bf16x4 __attribute__((ext_vector_type(4)));
typedef float  f32x4  __attribute__((ext_vector_type(4)));

// ---------------- dtype detection ----------------
// flags[0] = 1 if float tensors are bf16, 0 if float32
// flags[1] = 1 if edge_index is int64, 0 if int32
__global__ __launch_bounds__(256) void detect_kernel(const void* __restrict__ x,
                                                     const int* __restrict__ ei,
                                                     int* __restrict__ flags) {
    __shared__ int s_f32_evidence;
    __shared__ int s_odd_nonzero;
    int t = threadIdx.x;
    if (t == 0) { s_f32_evidence = 0; s_odd_nonzero = 0; }
    __syncthreads();
    const bf16* xb = (const bf16*)x;
    int local_f32 = 0;
    for (int i = t; i < 4096; i += 256) {
        float v = fabsf((float)xb[i]);
        if (!(v < 1e4f)) local_f32 = 1;   // huge / inf / NaN -> data is f32
    }
    if (local_f32) atomicOr(&s_f32_evidence, 1);
    int local_odd = 0;
    for (int k = t; k < 1024; k += 256) {
        if (ei[2 * k + 1] != 0) local_odd = 1;   // nonzero odd word -> int32 data
    }
    if (local_odd) atomicOr(&s_odd_nonzero, 1);
    __syncthreads();
    if (t == 0) {
        flags[0] = s_f32_evidence ? 0 : 1;
        flags[1] = s_odd_nonzero ? 0 : 1;
    }
}

// edge accessor honoring int32 vs int64 storage. which: 0=src row, 1=dst row.
__device__ __forceinline__ int edge_at(const int* __restrict__ ei, int which, int i,
                                       int is64) {
    if (is64) return ei[2 * (which * EDGES + i)];   // little-endian low word
    return ei[which * EDGES + i];
}

// ---------------- degree / dinv ----------------
__global__ __launch_bounds__(256) void deg_count(const int* __restrict__ ei,
                                                 int* __restrict__ deg, int e,
                                                 const int* __restrict__ flags) {
    int i = blockIdx.x * 256 + threadIdx.x;
    if (i < e) {
        int d = edge_at(ei, 1, i, flags[1]);
        if (d >= 0 && d < NODES) atomicAdd(&deg[d], 1);
    }
}

__global__ __launch_bounds__(256) void deg_to_dinv(const int* __restrict__ deg,
                                                   float* __restrict__ dinv, int n) {
    int i = blockIdx.x * 256 + threadIdx.x;
    if (i < n) dinv[i] = rsqrtf((float)deg[i] + 1.0f);  // +1 = self-loop
}

// ---------------- exclusive scan (3 kernels) to build col_ptr ----------------
__global__ __launch_bounds__(1024) void scan1(const int* __restrict__ deg,
                                              int* __restrict__ col_ptr,
                                              int* __restrict__ blksum, int n) {
    __shared__ int sm[1024];
    int t = threadIdx.x;
    int i = blockIdx.x * 1024 + t;
    int v = (i < n) ? deg[i] : 0;
    sm[t] = v;
    __syncthreads();
    for (int off = 1; off < 1024; off <<= 1) {
        int u = (t >= off) ? sm[t - off] : 0;
        __syncthreads();
        sm[t] += u;
        __syncthreads();
    }
    if (i <= n) col_ptr[i] = sm[t] - v;
    if (t == 1023) blksum[blockIdx.x] = sm[t];
}

__global__ void scan2(int* blk, int nblk) {
    if (threadIdx.x == 0 && blockIdx.x == 0) {
        int run = 0;
        for (int b = 0; b < nblk; ++b) { int t = blk[b]; blk[b] = run; run += t; }
    }
}

__global__ __launch_bounds__(256) void scan3(int* __restrict__ col_ptr,
                                             const int* __restrict__ blkoff,
                                             int* __restrict__ cursor, int n) {
    int i = blockIdx.x * 256 + threadIdx.x;
    if (i <= n) {
        int v = col_ptr[i] + blkoff[i >> 10];
        col_ptr[i] = v;
        if (i < n) cursor[i] = v;
    }
}

// ---------------- CSR fill: bucket src by dst ----------------
__global__ __launch_bounds__(256) void fill_csr(const int* __restrict__ ei,
                                                int* __restrict__ cursor,
                                                int* __restrict__ col_idx, int e,
                                                const int* __restrict__ flags) {
    int i = blockIdx.x * 256 + threadIdx.x;
    if (i < e) {
        int is64 = flags[1];
        int s = edge_at(ei, 0, i, is64);
        int d = edge_at(ei, 1, i, is64);
        if (s >= 0 && s < NODES && d >= 0 && d < NODES) {
            int pos = atomicAdd(&cursor[d], 1);
            col_idx[pos] = s;
        }
    }
}

// ---------------- pack W into MFMA B-fragment order (dtype-aware read) ----------------
__global__ __launch_bounds__(256) void pack_w(const void* __restrict__ W,
                                              bf16* __restrict__ Wp, int K,
                                              const int* __restrict__ flags) {
    int idx = blockIdx.x * 256 + threadIdx.x;
    if (idx >= K * 256) return;
    int j    = idx & 7;
    int lane = (idx >> 3) & 63;
    int ct   = (idx >> 9) & 15;
    int kt   = idx >> 13;
    int k = kt * 32 + (lane >> 4) * 8 + j;
    int n = ct * 16 + (lane & 15);
    bf16 v;
    if (flags[0]) v = ((const bf16*)W)[k * 256 + n];
    else          v = (bf16)(((const float*)W)[k * 256 + n]);
    Wp[idx] = v;
}

// ---------------- bias convert to bf16 ----------------
__global__ __launch_bounds__(256) void cvt_bias(const void* __restrict__ b,
                                                bf16* __restrict__ o, int n,
                                                const int* __restrict__ flags) {
    int i = blockIdx.x * 256 + threadIdx.x;
    if (i < n) {
        if (flags[0]) o[i] = ((const bf16*)b)[i];
        else          o[i] = (bf16)(((const float*)b)[i]);
    }
}

// ---------------- GEMM: out = (A[N,K] @ W[K,256]) (+opt *dinv[row], +opt bias) ----------------
// a_dyn: A dtype follows flags[0] (else A is bf16 ws buffer)
// out_dyn: out dtype follows flags[0] (else bf16 ws buffer)
__global__ __launch_bounds__(256) void gemm_kernel(const void* __restrict__ Av,
                                                   const bf16* __restrict__ Wp,
                                                   int K, int nrows,
                                                   const float* __restrict__ dinv,
                                                   const bf16* __restrict__ bias,
                                                   void* __restrict__ outv,
                                                   const int* __restrict__ flags,
                                                   int a_dyn, int out_dyn) {
    int fl0 = flags[0];
    int a_f32   = a_dyn   && (fl0 == 0);
    int out_f32 = out_dyn && (fl0 == 0);

    int wave = threadIdx.x >> 6;
    int lane = threadIdx.x & 63;
    int row0 = blockIdx.x * 64 + wave * 16;

    int ar  = row0 + (lane & 15);
    int arc = ar < nrows ? ar : (nrows - 1);
    int ak  = (lane >> 4) * 8;

    f32x4 acc[16];
    f32x4 z = {0.f, 0.f, 0.f, 0.f};
#pragma unroll
    for (int i = 0; i < 16; ++i) acc[i] = z;

    const bf16*  Ab = (const bf16*)Av  + (size_t)arc * K + ak;
    const float* Af = (const float*)Av + (size_t)arc * K + ak;

    int ktiles = K >> 5;
    for (int kt = 0; kt < ktiles; ++kt) {
        bf16x8 af;
        if (!a_f32) {
            af = *(const bf16x8*)(Ab + kt * 32);
        } else {
            const float* p = Af + kt * 32;
            f32x4 lo = *(const f32x4*)p;
            f32x4 hi = *(const f32x4*)(p + 4);
            af[0] = (bf16)lo[0]; af[1] = (bf16)lo[1]; af[2] = (bf16)lo[2]; af[3] = (bf16)lo[3];
            af[4] = (bf16)hi[0]; af[5] = (bf16)hi[1]; af[6] = (bf16)hi[2]; af[7] = (bf16)hi[3];
        }
        const bf16* wb = Wp + ((size_t)kt * 16 * 512) + lane * 8;
#pragma unroll
        for (int ct = 0; ct < 16; ++ct) {
            bf16x8 bfv = *(const bf16x8*)(wb + ct * 512);
            acc[ct] = __builtin_amdgcn_mfma_f32_16x16x32_bf16(af, bfv, acc[ct], 0, 0, 0);
        }
    }

    // C/D layout: col = ct*16 + (lane&15), row = row0 + (lane>>4)*4 + r
    int rbase = row0 + (lane >> 4) * 4;
    int cbase = lane & 15;
#pragma unroll
    for (int r = 0; r < 4; ++r) {
        int row = rbase + r;
        if (row >= nrows) continue;
        float s = dinv ? dinv[row] : 1.0f;
#pragma unroll
        for (int ct = 0; ct < 16; ++ct) {
            int col = ct * 16 + cbase;
            float v = acc[ct][r] * s;
            if (bias) v += (float)bias[col];
            size_t off = (size_t)row * 256 + col;
            if (out_f32) ((float*)outv)[off] = v;
            else         ((bf16*)outv)[off]  = (bf16)v;
        }
    }
}

// ---------------- gather: one wave per node, fused epilogue ----------------
// out[n] = relu(dinv[n]*(sum_{s in N(n)} Xs[s] + Xs[n]) + bias [+ proj[n]])
// io_dyn: proj/out dtype follows flags[0] (else bf16 ws buffers)
__global__ __launch_bounds__(256) void gather_kernel(const int* __restrict__ col_ptr,
                                                     const int* __restrict__ col_idx,
                                                     const bf16* __restrict__ Xs,
                                                     const float* __restrict__ dinv,
                                                     const bf16* __restrict__ bias,
                                                     const void* __restrict__ proj,
                                                     void* __restrict__ outv, int n,
                                                     const int* __restrict__ flags,
                                                     int io_dyn) {
    int io_f32 = io_dyn && (flags[0] == 0);
    int wid  = (int)((blockIdx.x * 256 + threadIdx.x) >> 6);
    int lane = threadIdx.x & 63;
    if (wid >= n) return;
    int beg = col_ptr[wid], end = col_ptr[wid + 1];
    int c = lane * 4;

    f32x4 acc = {0.f, 0.f, 0.f, 0.f};
    int e = beg;
    for (; e + 2 <= end; e += 2) {
        int s0 = col_idx[e];
        int s1 = col_idx[e + 1];
        bf16x4 v0 = *(const bf16x4*)(Xs + (size_t)s0 * 256 + c);
        bf16x4 v1 = *(const bf16x4*)(Xs + (size_t)s1 * 256 + c);
#pragma unroll
        for (int k = 0; k < 4; ++k) acc[k] += (float)v0[k] + (float)v1[k];
    }
    if (e < end) {
        int s0 = col_idx[e];
        bf16x4 v0 = *(const bf16x4*)(Xs + (size_t)s0 * 256 + c);
#pragma unroll
        for (int k = 0; k < 4; ++k) acc[k] += (float)v0[k];
    }

    bf16x4 selfv = *(const bf16x4*)(Xs + (size_t)wid * 256 + c);
    float di = dinv[wid];
    size_t base = (size_t)wid * 256 + c;

    f32x4 res;
#pragma unroll
    for (int k = 0; k < 4; ++k)
        res[k] = di * (acc[k] + (float)selfv[k]) + (float)bias[c + k];

    if (proj) {
        if (io_f32) {
            f32x4 pv = *(const f32x4*)((const float*)proj + base);
#pragma unroll
            for (int k = 0; k < 4; ++k) res[k] += pv[k];
        } else {
            bf16x4 pv = *(const bf16x4*)((const bf16*)proj + base);
#pragma unroll
            for (int k = 0; k < 4; ++k) res[k] += (float)pv[k];
        }
    }

    if (io_f32) {
        f32x4 o;
#pragma unroll
        for (int k = 0; k < 4; ++k) o[k] = fmaxf(res[k], 0.0f);
        *(f32x4*)((float*)outv + base) = o;
    } else {
        bf16x4 o;
#pragma unroll
        for (int k = 0; k < 4; ++k) o[k] = (bf16)fmaxf(res[k], 0.0f);
        *(bf16x4*)((bf16*)outv + base) = o;
    }
}

__global__ __launch_bounds__(256) void zero_out(bf16* out, int nelem) {
    int i = blockIdx.x * 256 + threadIdx.x;
    if (i < nelem) out[i] = (bf16)0.0f;
}

extern "C" void kernel_launch(void* const* d_in, const int* in_sizes, int n_in,
                              void* d_out, int out_size, void* d_ws, size_t ws_size,
                              hipStream_t stream) {
    const void* x   = d_in[0];
    const int*  ei  = (const int*)d_in[1];
    const void* W1  = d_in[2];
    const void* b1  = d_in[3];
    const void* W2  = d_in[4];
    const void* b2  = d_in[5];
    const void* Wp  = d_in[6];
    const void* bp  = d_in[7];

    const size_t NEEDED = 401408ull * 3 + 1024 + 1024 + 6400000 + 65536 + 131072 + 65536
                        + 2048 + 51200000ull * 2;  // ~110.3 MB
    if (ws_size < NEEDED) {
        zero_out<<<(NODES * 256 + 255) / 256, 256, 0, stream>>>((bf16*)d_out, NODES * 256);
        return;
    }
    char* w = (char*)d_ws;
    int*   col_ptr = (int*)w;   w += 401408;   // N+1 ints
    int*   cursor  = (int*)w;   w += 401408;   // deg, then fill cursors
    float* dinv    = (float*)w; w += 401408;
    int*   blk     = (int*)w;   w += 1024;
    int*   flags   = (int*)w;   w += 1024;
    int*   col_idx = (int*)w;   w += 6400000;  // E ints
    bf16*  W1p     = (bf16*)w;  w += 65536;
    bf16*  W2p     = (bf16*)w;  w += 131072;
    bf16*  Wpp     = (bf16*)w;  w += 65536;
    bf16*  b1b     = (bf16*)w;  w += 512;
    bf16*  b2b     = (bf16*)w;  w += 512;
    bf16*  bpb     = (bf16*)w;  w += 1024;
    bf16*  bufA    = (bf16*)w;  w += 51200000; // scaled XW
    bf16*  bufC    = (bf16*)w;  w += 51200000; // H1

    const int NBLK = (NODES + 1 + 1023) / 1024;  // 98

    // 0) detect dtypes
    detect_kernel<<<1, 256, 0, stream>>>(x, ei, flags);

    // 1) degree (into cursor) -> dinv
    hipMemsetAsync(cursor, 0, (size_t)NODES * 4, stream);
    deg_count<<<(EDGES + 255) / 256, 256, 0, stream>>>(ei, cursor, EDGES, flags);
    deg_to_dinv<<<(NODES + 255) / 256, 256, 0, stream>>>(cursor, dinv, NODES);

    // 2) CSR build
    scan1<<<NBLK, 1024, 0, stream>>>(cursor, col_ptr, blk, NODES);
    scan2<<<1, 64, 0, stream>>>(blk, NBLK);
    scan3<<<(NODES + 256) / 256, 256, 0, stream>>>(col_ptr, blk, cursor, NODES);
    fill_csr<<<(EDGES + 255) / 256, 256, 0, stream>>>(ei, cursor, col_idx, EDGES, flags);

    // 3) pack weights + biases
    pack_w<<<FIN, 256, 0, stream>>>(W1, W1p, FIN, flags);
    pack_w<<<FOUT, 256, 0, stream>>>(W2, W2p, FOUT, flags);
    pack_w<<<FIN, 256, 0, stream>>>(Wp, Wpp, FIN, flags);
    cvt_bias<<<1, 256, 0, stream>>>(b1, b1b, 256, flags);
    cvt_bias<<<1, 256, 0, stream>>>(b2, b2b, 256, flags);
    cvt_bias<<<1, 256, 0, stream>>>(bp, bpb, 256, flags);

    const int gemm_grid = (NODES + 63) / 64;
    const int gather_grid = (NODES + 3) / 4;

    // 4) conv1: bufA = (x@W1)*dinv ; bufC = relu(dinv*(agg+self)+b1)
    gemm_kernel<<<gemm_grid, 256, 0, stream>>>(x, W1p, FIN, NODES, dinv, nullptr,
                                               bufA, flags, /*a_dyn=*/1, /*out_dyn=*/0);
    gather_kernel<<<gather_grid, 256, 0, stream>>>(col_ptr, col_idx, bufA, dinv, b1b,
                                                   nullptr, bufC, NODES, flags, 0);

    // 5) conv2 pre: bufA = (bufC@W2)*dinv ; proj = x@Wp + bp -> d_out (dtype per flags)
    gemm_kernel<<<gemm_grid, 256, 0, stream>>>(bufC, W2p, FOUT, NODES, dinv, nullptr,
                                               bufA, flags, 0, 0);
    gemm_kernel<<<gemm_grid, 256, 0, stream>>>(x, Wpp, FIN, NODES, nullptr, bpb,
                                               d_out, flags, 1, /*out_dyn=*/1);

    // 6) out = relu(dinv*(agg+self) + b2 + proj)
    gather_kernel<<<gather_grid, 256, 0, stream>>>(col_ptr, col_idx, bufA, dinv, b2b,
                                                   d_out, d_out, NODES, flags, 1);
}